// Round 9
// baseline (4356.426 us; speedup 1.0000x reference)
//
#include <hip/hip_runtime.h>
#include <hip/hip_bf16.h>
#include <stdint.h>

typedef unsigned short u16;
typedef __attribute__((ext_vector_type(8))) unsigned short u16x8;
typedef __attribute__((ext_vector_type(4))) float f32x4;

#define CB   4
#define CC   256
#define CHW  4096
#define CNQ  4097
#define NQP  150
#define CHID 1024

// ---------------- workspace layout (bytes) ----------------
#define XT_OFF    0ul                                   // bf16 [B][4097][256]
#define EXE_OFF   (XT_OFF   + 8390656ul)                // f32  [B][256]
#define HEAT_OFF  (EXE_OFF  + 4096ul)                   // f32  [B][4096]
#define QID_OFF   (HEAT_OFF + 65536ul)                  // int  [B][160]

__device__ __forceinline__ float b2f(u16 x){
  unsigned u = ((unsigned)x) << 16; float f; __builtin_memcpy(&f, &u, 4); return f;
}
__device__ __forceinline__ u16 f2b(float f){
  __hip_bfloat16 h = __float2bfloat16(f); u16 r; __builtin_memcpy(&r, &h, 2); return r;
}
__device__ __forceinline__ u16x8 cvt8(f32x4 a, f32x4 b){
  u16x8 v;
  v[0]=f2b(a[0]); v[1]=f2b(a[1]); v[2]=f2b(a[2]); v[3]=f2b(a[3]);
  v[4]=f2b(b[0]); v[5]=f2b(b[1]); v[6]=f2b(b[2]); v[7]=f2b(b[3]);
  return v;
}

// ---------------- K0: exemplar mean (f32 in) ----------------
__global__ void exe_prep_k(const float* __restrict__ exe, float* __restrict__ exeF,
                           u16* __restrict__ Xt){
  int b = blockIdx.x, c = threadIdx.x;
  const float* p = exe + (b*CC + c)*49;
  float s = 0.f;
  for (int i = 0; i < 49; i++) s += p[i];
  float m = s / 49.f;
  exeF[b*CC + c] = m;
  Xt[(size_t)b*CNQ*CC + (size_t)CHW*CC + c] = f2b(m);
}

// ---------------- K1: 64x64 tiled transpose, f32 src -> bf16 dst -------------
__global__ void transpose64_k(const float* __restrict__ src, u16* __restrict__ dst,
                              int srcLd, long srcBatch, int dstLd, long dstBatch){
  __shared__ u16 tile[64][72];
  int c0 = blockIdx.x*64, m0 = blockIdx.y*64, b = blockIdx.z;
  const float* S = src + (long)b*srcBatch;
  u16* D = dst + (long)b*dstBatch;
  int t = threadIdx.x;
  int r = t >> 2, q = t & 3;
  for (int uu = q; uu < 8; uu += 4){
    const float* p = S + (long)(c0+r)*srcLd + m0 + uu*8;
    f32x4 a0 = *(const f32x4*)p;
    f32x4 a1 = *(const f32x4*)(p + 4);
    *(u16x8*)&tile[r][uu*8] = cvt8(a0, a1);
  }
  __syncthreads();
  for (int uu = q; uu < 8; uu += 4){
    u16x8 v;
    #pragma unroll
    for (int e = 0; e < 8; e++) v[e] = tile[uu*8 + e][r];
    *(u16x8*)(D + (long)(m0+r)*dstLd + c0 + uu*8) = v;
  }
}

// ---------------- K2: self-contained heat: exe-mean -> z -> heat -> hm -------
__global__ void heat2_k(const float* __restrict__ exe, const float* __restrict__ S,
                        const float* __restrict__ imgf,
                        float* __restrict__ heat, float* __restrict__ out_img){
  int b = blockIdx.y;
  int t = threadIdx.x;
  __shared__ float em[CC];
  __shared__ float zl[CC];
  {
    const float* p = exe + ((long)b*CC + t)*49;
    float s = 0.f;
    for (int i = 0; i < 49; i++) s += p[i];
    em[t] = s / 49.f;
  }
  __syncthreads();
  {
    const float* Sr = S + (long)t*CC;
    float s = 0.f;
    for (int d = 0; d < CC; d++) s += Sr[d] * em[d];
    zl[t] = s;
  }
  __syncthreads();
  int m = blockIdx.x*256 + t;
  const float* base = imgf + (long)b*CC*CHW + m;
  float s = 0.f;
  for (int c = 0; c < CC; c++) s += base[(long)c*CHW] * zl[c];
  heat[b*CHW + m] = s;
  out_img[(long)b*257*CHW + (long)256*CHW + m] = s;
}

// ---------------- K3: NMS + top-150 (bitonic, value desc / index asc) --------
__global__ __launch_bounds__(1024) void topk_k(const float* __restrict__ heat,
                                               int* __restrict__ qids,
                                               float* __restrict__ qbuf,
                                               float* __restrict__ out_coords){
  int b = blockIdx.x, t = threadIdx.x;
  __shared__ unsigned long long sk[4096];
  const float* hb = heat + (long)b*CHW;
  for (int p = t; p < 4096; p += 1024){
    int i = p >> 6, j = p & 63;
    float h = hb[p];
    bool ismax = false;
    if (i >= 1 && i < 63 && j >= 1 && j < 63){
      ismax = (h >= hb[p+64]) && (h > hb[p-64]) && (h >= hb[p+1]) && (h > hb[p-1]);
    }
    float sup = ismax ? h : (h - 1e9f);
    unsigned u = __float_as_uint(sup);
    u = (u & 0x80000000u) ? ~u : (u | 0x80000000u);
    unsigned long long key = ((unsigned long long)u << 32) | (unsigned)(0xFFFFFFFFu - (unsigned)p);
    sk[p] = ~key;                       // ascending sort of ~key == desired order
  }
  __syncthreads();
  for (int k = 2; k <= 4096; k <<= 1){
    for (int j = k >> 1; j > 0; j >>= 1){
      for (int tt = t; tt < 2048; tt += 1024){
        int i1 = 2*tt - (tt & (j-1));
        int i2 = i1 + j;
        unsigned long long a = sk[i1], c = sk[i2];
        bool up = ((i1 & k) == 0);
        if (up ? (a > c) : (a < c)){ sk[i1] = c; sk[i2] = a; }
      }
      __syncthreads();
    }
  }
  if (t < NQP){
    unsigned long long key = ~sk[t];
    int p = (int)(0xFFFFFFFFu - (unsigned)(key & 0xFFFFFFFFull));
    qids[b*160 + t] = p;
    out_coords[((long)b*NQP + t)*2 + 0] = (float)(p >> 6);
    out_coords[((long)b*NQP + t)*2 + 1] = (float)(p & 63);
    qbuf[((long)b*NQP + t)*257 + 256] = hb[p];
  }
}

// ---------------- K4: simple attention (layout-unambiguous), f32 out ---------
__global__ __launch_bounds__(256) void flash_simple_k(
    const u16* __restrict__ Xt, const float* __restrict__ S,
    const float* __restrict__ imgf, const float* __restrict__ maskp,
    const float* __restrict__ Wv, const float* __restrict__ exeF,
    const int* __restrict__ qids,
    float* __restrict__ out_img, float* __restrict__ qbuf){
  __shared__ float Qs[4][256];
  __shared__ float Tn[4][256];
  __shared__ u16  Xl[64][264];
  __shared__ float pl[4][64];
  __shared__ float al4[4], linv4[4], sex4[4];
  __shared__ int qid_l[160];
  __shared__ int qix_l[4];

  int b = blockIdx.y;
  int m0 = blockIdx.x * 4;
  int t = threadIdx.x;
  int wv = t >> 6;
  int lane = t & 63;

  if (t < 160) qid_l[t] = (t < NQP) ? qids[b*160 + t] : -1;

  {
    const float* base = imgf + ((long)b*CC + t)*CHW + m0;
    #pragma unroll
    for (int r = 0; r < 4; r++) Tn[r][t] = base[r];
  }
  __syncthreads();

  {
    float acc[4] = {0.f,0.f,0.f,0.f};
    for (int k = 0; k < CC; k++){
      float sv = S[(long)k*CC + t];
      #pragma unroll
      for (int r = 0; r < 4; r++) acc[r] += Tn[r][k] * sv;
    }
    #pragma unroll
    for (int r = 0; r < 4; r++) Qs[r][t] = acc[r];
  }
  __syncthreads();

  {
    float part = 0.f;
    for (int c = lane; c < CC; c += 64) part += Qs[wv][c] * exeF[b*CC + c];
    #pragma unroll
    for (int d = 1; d < 64; d <<= 1) part += __shfl_xor(part, d, 64);
    if (lane == 0) sex4[wv] = part;
  }
  __syncthreads();

  float m_run = sex4[wv];
  float l_run = 1.f;
  float rowAllowed = (maskp[b*CHW + m0 + wv] == 1.0f) ? 1.f : 0.f;
  float Treg[4];
  #pragma unroll
  for (int r = 0; r < 4; r++) Treg[r] = exeF[b*CC + t];

  for (int nt = 0; nt < 64; nt++){
    int n0 = nt*64;
    __syncthreads();
    #pragma unroll
    for (int it = 0; it < 8; it++){
      int idx = t + 256*it;
      int n = idx >> 5, ch = idx & 31;
      *(u16x8*)&Xl[n][ch*8] = *(const u16x8*)(Xt + ((long)b*CNQ + n0 + n)*CC + ch*8);
    }
    __syncthreads();
    int n = n0 + lane;
    float s = 0.f;
    for (int c = 0; c < CC; c += 8){
      u16x8 xv = *(const u16x8*)&Xl[lane][c];
      #pragma unroll
      for (int e = 0; e < 8; e++) s += Qs[wv][c + e] * b2f(xv[e]);
    }
    float cm = (maskp[b*CHW + n] == 1.0f) ? 1.f : 0.f;
    float se = (rowAllowed * cm == 1.f) ? s : (s - 1e9f);
    float tm = se;
    #pragma unroll
    for (int d = 1; d < 64; d <<= 1) tm = fmaxf(tm, __shfl_xor(tm, d, 64));
    float newm = fmaxf(m_run, tm);
    float alf = expf(m_run - newm);
    float p = expf(se - newm);
    float rs = p;
    #pragma unroll
    for (int d = 1; d < 64; d <<= 1) rs += __shfl_xor(rs, d, 64);
    l_run = l_run * alf + rs;
    m_run = newm;
    pl[wv][lane] = p;
    if (lane == 0) al4[wv] = alf;
    __syncthreads();
    float acc[4] = {0.f,0.f,0.f,0.f};
    for (int j = 0; j < 64; j++){
      float xv = b2f(Xl[j][t]);
      #pragma unroll
      for (int r = 0; r < 4; r++) acc[r] += pl[r][j] * xv;
    }
    #pragma unroll
    for (int r = 0; r < 4; r++) Treg[r] = Treg[r]*al4[r] + acc[r];
  }
  __syncthreads();
  if (lane == 0) linv4[wv] = 1.0f / l_run;
  if (t < 4){
    int m = m0 + t, f = -1;
    for (int i = 0; i < NQP; i++) if (qid_l[i] == m){ f = i; break; }
    qix_l[t] = f;
  }
  __syncthreads();
  #pragma unroll
  for (int r = 0; r < 4; r++) Tn[r][t] = Treg[r] * linv4[r];
  __syncthreads();

  float F[4] = {0.f,0.f,0.f,0.f};
  {
    const float* wr = Wv + (long)t*CC;
    for (int c = 0; c < CC; c++){
      float wvv = wr[c];
      #pragma unroll
      for (int r = 0; r < 4; r++) F[r] += Tn[r][c] * wvv;
    }
  }
  float* oi = out_img + (long)b*257*CHW;
  const float* fi = imgf + ((long)b*CC + t)*CHW + m0;
  #pragma unroll
  for (int r = 0; r < 4; r++){
    float v = F[r] + fi[r];
    oi[(long)t*CHW + m0 + r] = v;
    if (qix_l[r] >= 0) qbuf[((long)b*NQP + qix_l[r])*257 + t] = v;
  }
}

// ---------------- K5: fused LayerNorm + MLP head (all f32) -------------------
__global__ __launch_bounds__(256) void qhead_k(float* __restrict__ qbuf,
    const float* __restrict__ g, const float* __restrict__ be,
    const float* __restrict__ W1, const float* __restrict__ b1,
    const float* __restrict__ W2, const float* __restrict__ b2){
  int bi = blockIdx.x;
  int t = threadIdx.x, lane = t & 63, w = t >> 6;
  __shared__ float xl[257];
  __shared__ float hl[CHID];
  __shared__ float r1[4], r2[4];
  float* row = qbuf + (long)bi*257;
  float v0 = row[t];
  float v1 = (t == 0) ? row[256] : 0.f;
  float s = v0 + v1;
  #pragma unroll
  for (int d = 1; d < 64; d <<= 1) s += __shfl_xor(s, d, 64);
  if (lane == 0) r1[w] = s;
  __syncthreads();
  float mu = (r1[0]+r1[1]+r1[2]+r1[3]) / 257.f;
  float d0 = v0 - mu;
  float d1 = (t == 0) ? (v1 - mu) : 0.f;
  float vs = d0*d0 + d1*d1;
  #pragma unroll
  for (int d = 1; d < 64; d <<= 1) vs += __shfl_xor(vs, d, 64);
  if (lane == 0) r2[w] = vs;
  __syncthreads();
  float var = (r2[0]+r2[1]+r2[2]+r2[3]) / 257.f;
  float inv = 1.0f / sqrtf(var + 1e-5f);
  xl[t] = d0*inv*g[t] + be[t];
  if (t == 0) xl[256] = d1*inv*g[256] + be[256];
  __syncthreads();
  for (int h = t; h < CHID; h += 256){
    const float* wr = W1 + (long)h*257;
    float acc = b1[h];
    for (int c = 0; c < 257; c++) acc += wr[c] * xl[c];
    hl[h] = fmaxf(acc, 0.f);
  }
  __syncthreads();
  for (int o = t; o < 257; o += 256){
    const float* wr = W2 + (long)o*CHID;
    float acc = b2[o];
    for (int k = 0; k < CHID; k += 4){
      f32x4 wv = *(const f32x4*)(wr + k);
      acc += wv[0]*hl[k] + wv[1]*hl[k+1] + wv[2]*hl[k+2] + wv[3]*hl[k+3];
    }
    row[o] = acc;
  }
}

// ---------------- launch: input mapping by SIZE (robust to ordering) ---------
extern "C" void kernel_launch(void* const* d_in, const int* in_sizes, int n_in,
                              void* d_out, int out_size, void* d_ws, size_t ws_size,
                              hipStream_t stream){
  (void)out_size; (void)ws_size;
  int idxImg=-1, idxExe=-1, idxMask=-1, idxB1=-1;
  int idx65[2]={-1,-1}; int n65=0;
  int idx263[2]={-1,-1}; int n263=0;
  int idx257[3]={-1,-1,-1}; int n257=0;
  for (int i = 0; i < n_in; i++){
    int s = in_sizes[i];
    if      (s == 4194304) idxImg = i;
    else if (s == 50176)   idxExe = i;
    else if (s == 16384)   idxMask = i;
    else if (s == 1024)    idxB1 = i;
    else if (s == 65536)  { if (n65 < 2)  idx65[n65++] = i; }
    else if (s == 263168) { if (n263 < 2) idx263[n263++] = i; }
    else if (s == 257)    { if (n257 < 3) idx257[n257++] = i; }
  }
  const float* img  = (const float*)d_in[idxImg];
  const float* exe  = (const float*)d_in[idxExe];
  const float* mask = (const float*)d_in[idxMask];
  const float* S    = (const float*)d_in[idx65[0]];   // S before Wv in both dict & sorted order
  const float* Wv   = (const float*)d_in[idx65[1]];
  const float* W1   = (const float*)d_in[idx263[0]];  // W1 before W2 in both orders
  const float* W2   = (const float*)d_in[idx263[1]];
  const float* b1   = (const float*)d_in[idxB1];
  const float *lng, *lnb, *b2;
  if (idxImg == 0){           // dict order: ln_g, ln_b, b2
    lng = (const float*)d_in[idx257[0]];
    lnb = (const float*)d_in[idx257[1]];
    b2  = (const float*)d_in[idx257[2]];
  } else {                    // name-sorted: b2, ln_b, ln_g
    b2  = (const float*)d_in[idx257[0]];
    lnb = (const float*)d_in[idx257[1]];
    lng = (const float*)d_in[idx257[2]];
  }

  char* ws = (char*)d_ws;
  u16*   Xt   = (u16*)(ws + XT_OFF);
  float* exeF = (float*)(ws + EXE_OFF);
  float* heat = (float*)(ws + HEAT_OFF);
  int*   qids = (int*)(ws + QID_OFF);

  float* out      = (float*)d_out;                       // f32 outputs!
  float* out_img  = out;                                 // [4][257][4096]
  float* qbuf     = out + (size_t)CB*257*CHW;            // [4][150][257]
  float* out_crd  = qbuf + (size_t)CB*NQP*257;           // [4][150][2]

  exe_prep_k<<<dim3(CB), dim3(256), 0, stream>>>(exe, exeF, Xt);
  transpose64_k<<<dim3(4, 64, CB), dim3(256), 0, stream>>>(
      img, Xt, CHW, (long)CC*CHW, CC, (long)CNQ*CC);
  heat2_k<<<dim3(16, CB), dim3(256), 0, stream>>>(exe, S, img, heat, out_img);
  topk_k<<<dim3(CB), dim3(1024), 0, stream>>>(heat, qids, qbuf, out_crd);
  flash_simple_k<<<dim3(1024, CB), dim3(256), 0, stream>>>(
      Xt, S, img, mask, Wv, exeF, qids, out_img, qbuf);
  qhead_k<<<dim3(CB*NQP), dim3(256), 0, stream>>>(qbuf, lng, lnb, W1, b1, W2, b2);
}

// Round 10
// 908.745 us; speedup vs baseline: 4.7939x; 4.7939x over previous
//
#include <hip/hip_runtime.h>
#include <hip/hip_bf16.h>
#include <stdint.h>

typedef unsigned short u16;
typedef __attribute__((ext_vector_type(8))) unsigned short u16x8;
typedef __attribute__((ext_vector_type(8))) short short8;
typedef __attribute__((ext_vector_type(4))) float f32x4;

#define CB   4
#define CC   256
#define CHW  4096
#define CNQ  4097
#define NQP  150
#define CHID 1024

// ---------------- workspace layout (bytes) ----------------
#define XT_OFF    0ul                                   // bf16 [B][4097][256]
#define ST_OFF    (XT_OFF   + 8390656ul)                // bf16 [256][256] (S^T)
#define EXE_OFF   (ST_OFF   + 131072ul)                 // f32  [B][256]
#define HEAT_OFF  (EXE_OFF  + 4096ul)                   // f32  [B][4096]
#define QID_OFF   (HEAT_OFF + 65536ul)                  // int  [B][160]

__device__ __forceinline__ float b2f(u16 x){
  unsigned u = ((unsigned)x) << 16; float f; __builtin_memcpy(&f, &u, 4); return f;
}
__device__ __forceinline__ u16 f2b(float f){
  __hip_bfloat16 h = __float2bfloat16(f); u16 r; __builtin_memcpy(&r, &h, 2); return r;
}
__device__ __forceinline__ f32x4 mfma16(u16x8 a, u16x8 b, f32x4 c){
  short8 as, bs; __builtin_memcpy(&as, &a, 16); __builtin_memcpy(&bs, &b, 16);
  return __builtin_amdgcn_mfma_f32_16x16x32_bf16(as, bs, c, 0, 0, 0);
}
__device__ __forceinline__ u16x8 zero8(){
  u16x8 v;
  #pragma unroll
  for (int e = 0; e < 8; e++) v[e] = 0;
  return v;
}
__device__ __forceinline__ u16x8 cvt8(f32x4 a, f32x4 b){
  u16x8 v;
  v[0]=f2b(a[0]); v[1]=f2b(a[1]); v[2]=f2b(a[2]); v[3]=f2b(a[3]);
  v[4]=f2b(b[0]); v[5]=f2b(b[1]); v[6]=f2b(b[2]); v[7]=f2b(b[3]);
  return v;
}

// ---------------- K0: exemplar mean (f32 in) ----------------
__global__ void exe_prep_k(const float* __restrict__ exe, float* __restrict__ exeF,
                           u16* __restrict__ Xt){
  int b = blockIdx.x, c = threadIdx.x;
  const float* p = exe + (b*CC + c)*49;
  float s = 0.f;
  for (int i = 0; i < 49; i++) s += p[i];
  float m = s / 49.f;
  exeF[b*CC + c] = m;
  Xt[(size_t)b*CNQ*CC + (size_t)CHW*CC + c] = f2b(m);
}

// ---------------- K1: 64x64 tiled transpose, f32 src -> bf16 dst -------------
__global__ void transpose64_k(const float* __restrict__ src, u16* __restrict__ dst,
                              int srcLd, long srcBatch, int dstLd, long dstBatch){
  __shared__ u16 tile[64][72];
  int c0 = blockIdx.x*64, m0 = blockIdx.y*64, b = blockIdx.z;
  const float* S = src + (long)b*srcBatch;
  u16* D = dst + (long)b*dstBatch;
  int t = threadIdx.x;
  int r = t >> 2, q = t & 3;
  for (int uu = q; uu < 8; uu += 4){
    const float* p = S + (long)(c0+r)*srcLd + m0 + uu*8;
    f32x4 a0 = *(const f32x4*)p;
    f32x4 a1 = *(const f32x4*)(p + 4);
    *(u16x8*)&tile[r][uu*8] = cvt8(a0, a1);
  }
  __syncthreads();
  for (int uu = q; uu < 8; uu += 4){
    u16x8 v;
    #pragma unroll
    for (int e = 0; e < 8; e++) v[e] = tile[uu*8 + e][r];
    *(u16x8*)(D + (long)(m0+r)*dstLd + c0 + uu*8) = v;
  }
}

// ---------------- K2: self-contained heat: exe-mean -> z -> heat -> hm -------
__global__ void heat2_k(const float* __restrict__ exe, const float* __restrict__ S,
                        const float* __restrict__ imgf,
                        float* __restrict__ heat, float* __restrict__ out_img){
  int b = blockIdx.y;
  int t = threadIdx.x;
  __shared__ float em[CC];
  __shared__ float zl[CC];
  {
    const float* p = exe + ((long)b*CC + t)*49;
    float s = 0.f;
    for (int i = 0; i < 49; i++) s += p[i];
    em[t] = s / 49.f;
  }
  __syncthreads();
  {
    const float* Sr = S + (long)t*CC;
    float s = 0.f;
    for (int d = 0; d < CC; d++) s += Sr[d] * em[d];
    zl[t] = s;
  }
  __syncthreads();
  int m = blockIdx.x*256 + t;
  const float* base = imgf + (long)b*CC*CHW + m;
  float s = 0.f;
  for (int c = 0; c < CC; c++) s += base[(long)c*CHW] * zl[c];
  heat[b*CHW + m] = s;
  out_img[(long)b*257*CHW + (long)256*CHW + m] = s;
}

// ---------------- K3: NMS + top-150 (bitonic, value desc / index asc) --------
__global__ __launch_bounds__(1024) void topk_k(const float* __restrict__ heat,
                                               int* __restrict__ qids,
                                               float* __restrict__ qbuf,
                                               float* __restrict__ out_coords){
  int b = blockIdx.x, t = threadIdx.x;
  __shared__ unsigned long long sk[4096];
  const float* hb = heat + (long)b*CHW;
  for (int p = t; p < 4096; p += 1024){
    int i = p >> 6, j = p & 63;
    float h = hb[p];
    bool ismax = false;
    if (i >= 1 && i < 63 && j >= 1 && j < 63){
      ismax = (h >= hb[p+64]) && (h > hb[p-64]) && (h >= hb[p+1]) && (h > hb[p-1]);
    }
    float sup = ismax ? h : (h - 1e9f);
    unsigned u = __float_as_uint(sup);
    u = (u & 0x80000000u) ? ~u : (u | 0x80000000u);
    unsigned long long key = ((unsigned long long)u << 32) | (unsigned)(0xFFFFFFFFu - (unsigned)p);
    sk[p] = ~key;                       // ascending sort of ~key == desired order
  }
  __syncthreads();
  for (int k = 2; k <= 4096; k <<= 1){
    for (int j = k >> 1; j > 0; j >>= 1){
      for (int tt = t; tt < 2048; tt += 1024){
        int i1 = 2*tt - (tt & (j-1));
        int i2 = i1 + j;
        unsigned long long a = sk[i1], c = sk[i2];
        bool up = ((i1 & k) == 0);
        if (up ? (a > c) : (a < c)){ sk[i1] = c; sk[i2] = a; }
      }
      __syncthreads();
    }
  }
  if (t < NQP){
    unsigned long long key = ~sk[t];
    int p = (int)(0xFFFFFFFFu - (unsigned)(key & 0xFFFFFFFFull));
    qids[b*160 + t] = p;
    out_coords[((long)b*NQP + t)*2 + 0] = (float)(p >> 6);
    out_coords[((long)b*NQP + t)*2 + 1] = (float)(p & 63);
    qbuf[((long)b*NQP + t)*257 + 256] = hb[p];
  }
}

// ---------------- K4: MFMA flash attention + output assembly -----------------
// Q = Xrows·S^T (in-block MFMA), scores = Q·Xt^T, online softmax w/ mask bias,
// T += P·Ktile (accumulated over tiles), final O = T_norm·Wv^T + img (f32).
__global__ __launch_bounds__(256, 2) void flash_k(
    const u16* __restrict__ Xt, const u16* __restrict__ St,
    const float* __restrict__ imgf, const float* __restrict__ maskp,
    const float* __restrict__ Wv, const int* __restrict__ qids,
    float* __restrict__ out_img, float* __restrict__ qbuf){
  __shared__ u16 kp_tile[64*256];   // Q/T round-trip + K-tile; P-tile aliases first 8KB
  __shared__ u16 kt_tile[256*64];   // K^T tile [c][n]; aliased as qid list at end
  int b = blockIdx.y;
  int m0 = blockIdx.x*64;
  int t = threadIdx.x, w = t >> 6, lane = t & 63, l15 = lane & 15, qd = lane >> 4;
  f32x4 zero4 = {0.f,0.f,0.f,0.f};

  // ---- Phase 0: Q[64][256] = Xrows · St^T  (= X·S) ----
  {
    f32x4 D[16];
    #pragma unroll
    for (int i = 0; i < 16; i++) D[i] = zero4;
    const u16* arow = Xt + ((long)b*CNQ + (m0 + w*16 + l15))*CC;
    #pragma unroll
    for (int ks = 0; ks < 8; ks++){
      u16x8 af = *(const u16x8*)(arow + ks*32 + qd*8);
      #pragma unroll
      for (int ds = 0; ds < 16; ds++){
        u16x8 bf_ = *(const u16x8*)(St + (long)(ds*16 + l15)*CC + ks*32 + qd*8);
        D[ds] = mfma16(af, bf_, D[ds]);
      }
    }
    #pragma unroll
    for (int ds = 0; ds < 16; ds++){
      #pragma unroll
      for (int r = 0; r < 4; r++){
        int prow = w*16 + qd*4 + r;
        int ccol = ds*16 + l15;
        kp_tile[prow*256 + ((ccol >> 3) ^ ((prow & 7)*4))*8 + (ccol & 7)] = f2b(D[ds][r]);
      }
    }
  }
  __syncthreads();
  u16x8 afrag[8];
  {
    int arl = w*16 + l15;
    #pragma unroll
    for (int ks = 0; ks < 8; ks++)
      afrag[ks] = *(const u16x8*)&kp_tile[arl*256 + (((ks*4 + qd)) ^ ((arl & 7)*4))*8];
  }
  __syncthreads();

  float rowAllowed[4], mi[4], li[4];
  #pragma unroll
  for (int r = 0; r < 4; r++){
    int m = m0 + w*16 + qd*4 + r;
    rowAllowed[r] = (maskp[b*CHW + m] == 1.0f) ? 1.f : 0.f;
    mi[r] = -1e30f; li[r] = 0.f;
  }
  f32x4 O[16];
  #pragma unroll
  for (int i = 0; i < 16; i++) O[i] = zero4;

  int srow = t >> 2, su = t & 3;   // K staging
  int vu = t & 7;                  // K^T staging

  for (int nt = 0; nt < 65; nt++){
    int n0 = nt*64;
    // ---- stage K tile (Xt rows n0..n0+63; row 4096 valid, beyond zero) ----
    {
      const u16* xrow = Xt + ((long)b*CNQ + (n0 + srow))*CC;
      bool valid = (n0 + srow) < CNQ;
      #pragma unroll
      for (int i = 0; i < 8; i++){
        int uu = su + 4*i;
        int pu = uu ^ ((srow & 7)*4);
        u16x8 v = zero8();
        if (valid) v = *(const u16x8*)(xrow + uu*8);
        *(u16x8*)&kp_tile[srow*256 + pu*8] = v;
      }
      // ---- stage K^T tile [c][n] from f32 img; last tile: col0 = exemplar ----
      bool nvalid = (n0 + 63) < CHW;
      #pragma unroll
      for (int j = 0; j < 8; j++){
        int c = (t >> 3) + 32*j;
        int pu2 = vu ^ (c & 7);
        u16x8 v = zero8();
        if (nvalid){
          const float* crow = imgf + ((long)b*CC + c)*CHW + n0 + vu*8;
          f32x4 a0 = *(const f32x4*)crow;
          f32x4 a1 = *(const f32x4*)(crow + 4);
          v = cvt8(a0, a1);
        } else if (vu == 0){
          v[0] = Xt[((long)b*CNQ + CHW)*CC + c];
        }
        *(u16x8*)&kt_tile[c*64 + pu2*8] = v;
      }
    }
    __syncthreads();   // (1) tiles ready

    // ---- QK^T ----
    f32x4 sc[4];
    #pragma unroll
    for (int i = 0; i < 4; i++) sc[i] = zero4;
    #pragma unroll
    for (int ks = 0; ks < 8; ks++){
      #pragma unroll
      for (int ns = 0; ns < 4; ns++){
        int n_l = ns*16 + l15;
        u16x8 bfrag = *(const u16x8*)&kp_tile[n_l*256 + (((ks*4 + qd)) ^ ((n_l & 7)*4))*8];
        sc[ns] = mfma16(afrag[ks], bfrag, sc[ns]);
      }
    }
    __syncthreads();   // (2) K reads done before P overwrites kp_tile

    // ---- mask bias + online softmax ----
    float sEff[4][4];
    #pragma unroll
    for (int ns = 0; ns < 4; ns++){
      int n = n0 + ns*16 + l15;
      bool inv = (n >= CNQ);
      bool isEx = (n == CHW);
      float cm = 0.f;
      if (!inv && !isEx) cm = (maskp[b*CHW + n] == 1.0f) ? 1.f : 0.f;
      #pragma unroll
      for (int r = 0; r < 4; r++){
        float s = sc[ns][r];
        float se;
        if (inv)        se = -1e30f;
        else if (isEx)  se = s;
        else            se = ((rowAllowed[r] != 0.f) && (cm != 0.f)) ? s : s - 1e9f;
        sEff[ns][r] = se;
      }
    }
    float al[4], nm[4];
    #pragma unroll
    for (int r = 0; r < 4; r++){
      float tm = fmaxf(fmaxf(sEff[0][r], sEff[1][r]), fmaxf(sEff[2][r], sEff[3][r]));
      #pragma unroll
      for (int d = 1; d < 16; d <<= 1) tm = fmaxf(tm, __shfl_xor(tm, d, 16));
      float newm = fmaxf(mi[r], tm);
      al[r] = (mi[r] < -1e29f) ? 0.f : expf(fmaxf(mi[r] - newm, -88.f));
      nm[r] = newm; mi[r] = newm;
    }
    #pragma unroll
    for (int r = 0; r < 4; r++){
      float rs = 0.f;
      int prow = w*16 + qd*4 + r;
      #pragma unroll
      for (int ns = 0; ns < 4; ns++){
        float p = expf(fmaxf(sEff[ns][r] - nm[r], -88.f));
        rs += p;
        int ccol = ns*16 + l15;
        kp_tile[prow*64 + ((ccol >> 3) ^ (prow & 7))*8 + (ccol & 7)] = f2b(p);
      }
      #pragma unroll
      for (int d = 1; d < 16; d <<= 1) rs += __shfl_xor(rs, d, 16);
      li[r] = li[r]*al[r] + rs;
    }
    __syncthreads();   // (3) P visible

    // ---- rescale T, then T += P·Ktile ----
    #pragma unroll
    for (int ds = 0; ds < 16; ds++){
      #pragma unroll
      for (int r = 0; r < 4; r++) O[ds][r] *= al[r];
    }
    #pragma unroll
    for (int ks = 0; ks < 2; ks++){
      int prow = w*16 + l15;
      u16x8 pf = *(const u16x8*)&kp_tile[prow*64 + (((ks*4 + qd)) ^ (prow & 7))*8];
      #pragma unroll
      for (int ds = 0; ds < 16; ds++){
        int c = ds*16 + l15;
        u16x8 vf = *(const u16x8*)&kt_tile[c*64 + (((ks*4 + qd)) ^ (c & 7))*8];
        O[ds] = mfma16(pf, vf, O[ds]);
      }
    }
    __syncthreads();   // (4) reads done before next staging
  }

  // ---- final: normalize T, round-trip to A-layout, project by Wv^T ----
  float linv[4];
  #pragma unroll
  for (int r = 0; r < 4; r++) linv[r] = (li[r] > 0.f) ? (1.0f / li[r]) : 0.f;
  #pragma unroll
  for (int ds = 0; ds < 16; ds++){
    #pragma unroll
    for (int r = 0; r < 4; r++){
      int prow = w*16 + qd*4 + r;
      int ccol = ds*16 + l15;
      kp_tile[prow*256 + ((ccol >> 3) ^ ((prow & 7)*4))*8 + (ccol & 7)] = f2b(O[ds][r]*linv[r]);
    }
  }
  int* qlds = (int*)kt_tile;
  if (t < NQP) qlds[t] = qids[b*160 + t];
  __syncthreads();
  u16x8 tfrag[8];
  {
    int arl = w*16 + l15;
    #pragma unroll
    for (int ks = 0; ks < 8; ks++)
      tfrag[ks] = *(const u16x8*)&kp_tile[arl*256 + (((ks*4 + qd)) ^ ((arl & 7)*4))*8];
  }
  f32x4 F[16];
  #pragma unroll
  for (int i = 0; i < 16; i++) F[i] = zero4;
  #pragma unroll
  for (int ks = 0; ks < 8; ks++){
    #pragma unroll
    for (int ds = 0; ds < 16; ds++){
      const float* wr = Wv + (long)(ds*16 + l15)*CC + ks*32 + qd*8;
      f32x4 w0 = *(const f32x4*)wr;
      f32x4 w1 = *(const f32x4*)(wr + 4);
      F[ds] = mfma16(tfrag[ks], cvt8(w0, w1), F[ds]);
    }
  }

  // ---- epilogue: f32 img_out + f32 query rows ----
  int qix[4];
  #pragma unroll
  for (int r = 0; r < 4; r++){
    int m = m0 + w*16 + qd*4 + r;
    int f = -1;
    for (int i = 0; i < NQP; i++) if (qlds[i] == m){ f = i; break; }
    qix[r] = f;
  }
  float* oi = out_img + (long)b*257*CHW;
  const float* fi = imgf + (long)b*CC*CHW;
  int mb = m0 + w*16 + qd*4;
  #pragma unroll
  for (int ds = 0; ds < 16; ds++){
    int d = ds*16 + l15;
    f32x4 ivals = *(const f32x4*)(fi + (long)d*CHW + mb);
    f32x4 ovals;
    #pragma unroll
    for (int r = 0; r < 4; r++){
      float v = F[ds][r] + ivals[r];
      ovals[r] = v;
      if (qix[r] >= 0) qbuf[((long)b*NQP + qix[r])*257 + d] = v;
    }
    *(f32x4*)(oi + (long)d*CHW + mb) = ovals;
  }
}

// ---------------- K5: fused LayerNorm + MLP head (all f32) -------------------
__global__ __launch_bounds__(256) void qhead_k(float* __restrict__ qbuf,
    const float* __restrict__ g, const float* __restrict__ be,
    const float* __restrict__ W1, const float* __restrict__ b1,
    const float* __restrict__ W2, const float* __restrict__ b2){
  int bi = blockIdx.x;
  int t = threadIdx.x, lane = t & 63, w = t >> 6;
  __shared__ float xl[257];
  __shared__ float hl[CHID];
  __shared__ float r1[4], r2[4];
  float* row = qbuf + (long)bi*257;
  float v0 = row[t];
  float v1 = (t == 0) ? row[256] : 0.f;
  float s = v0 + v1;
  #pragma unroll
  for (int d = 1; d < 64; d <<= 1) s += __shfl_xor(s, d, 64);
  if (lane == 0) r1[w] = s;
  __syncthreads();
  float mu = (r1[0]+r1[1]+r1[2]+r1[3]) / 257.f;
  float d0 = v0 - mu;
  float d1 = (t == 0) ? (v1 - mu) : 0.f;
  float vs = d0*d0 + d1*d1;
  #pragma unroll
  for (int d = 1; d < 64; d <<= 1) vs += __shfl_xor(vs, d, 64);
  if (lane == 0) r2[w] = vs;
  __syncthreads();
  float var = (r2[0]+r2[1]+r2[2]+r2[3]) / 257.f;
  float inv = 1.0f / sqrtf(var + 1e-5f);
  xl[t] = d0*inv*g[t] + be[t];
  if (t == 0) xl[256] = d1*inv*g[256] + be[256];
  __syncthreads();
  for (int h = t; h < CHID; h += 256){
    const float* wr = W1 + (long)h*257;
    float acc = b1[h];
    for (int c = 0; c < 257; c++) acc += wr[c] * xl[c];
    hl[h] = fmaxf(acc, 0.f);
  }
  __syncthreads();
  for (int o = t; o < 257; o += 256){
    const float* wr = W2 + (long)o*CHID;
    float acc = b2[o];
    for (int k = 0; k < CHID; k += 4){
      f32x4 wv = *(const f32x4*)(wr + k);
      acc += wv[0]*hl[k] + wv[1]*hl[k+1] + wv[2]*hl[k+2] + wv[3]*hl[k+3];
    }
    row[o] = acc;
  }
}

// ---------------- launch: input mapping by SIZE (robust to ordering) ---------
extern "C" void kernel_launch(void* const* d_in, const int* in_sizes, int n_in,
                              void* d_out, int out_size, void* d_ws, size_t ws_size,
                              hipStream_t stream){
  (void)out_size; (void)ws_size;
  int idxImg=-1, idxExe=-1, idxMask=-1, idxB1=-1;
  int idx65[2]={-1,-1}; int n65=0;
  int idx263[2]={-1,-1}; int n263=0;
  int idx257[3]={-1,-1,-1}; int n257=0;
  for (int i = 0; i < n_in; i++){
    int s = in_sizes[i];
    if      (s == 4194304) idxImg = i;
    else if (s == 50176)   idxExe = i;
    else if (s == 16384)   idxMask = i;
    else if (s == 1024)    idxB1 = i;
    else if (s == 65536)  { if (n65 < 2)  idx65[n65++] = i; }
    else if (s == 263168) { if (n263 < 2) idx263[n263++] = i; }
    else if (s == 257)    { if (n257 < 3) idx257[n257++] = i; }
  }
  const float* img  = (const float*)d_in[idxImg];
  const float* exe  = (const float*)d_in[idxExe];
  const float* mask = (const float*)d_in[idxMask];
  const float* S    = (const float*)d_in[idx65[0]];   // S before Wv in both dict & sorted order
  const float* Wv   = (const float*)d_in[idx65[1]];
  const float* W1   = (const float*)d_in[idx263[0]];  // W1 before W2 in both orders
  const float* W2   = (const float*)d_in[idx263[1]];
  const float* b1   = (const float*)d_in[idxB1];
  const float *lng, *lnb, *b2;
  if (idxImg == 0){           // dict order: ln_g, ln_b, b2
    lng = (const float*)d_in[idx257[0]];
    lnb = (const float*)d_in[idx257[1]];
    b2  = (const float*)d_in[idx257[2]];
  } else {                    // name-sorted: b2, ln_b, ln_g
    b2  = (const float*)d_in[idx257[0]];
    lnb = (const float*)d_in[idx257[1]];
    lng = (const float*)d_in[idx257[2]];
  }

  char* ws = (char*)d_ws;
  u16*   Xt   = (u16*)(ws + XT_OFF);
  u16*   St   = (u16*)(ws + ST_OFF);
  float* exeF = (float*)(ws + EXE_OFF);
  float* heat = (float*)(ws + HEAT_OFF);
  int*   qids = (int*)(ws + QID_OFF);

  float* out      = (float*)d_out;                       // f32 outputs
  float* out_img  = out;                                 // [4][257][4096]
  float* qbuf     = out + (size_t)CB*257*CHW;            // [4][150][257]
  float* out_crd  = qbuf + (size_t)CB*NQP*257;           // [4][150][2]

  exe_prep_k<<<dim3(CB), dim3(256), 0, stream>>>(exe, exeF, Xt);
  transpose64_k<<<dim3(4, 64, CB), dim3(256), 0, stream>>>(
      img, Xt, CHW, (long)CC*CHW, CC, (long)CNQ*CC);
  transpose64_k<<<dim3(4, 4, 1), dim3(256), 0, stream>>>(
      S, St, CC, 0, CC, 0);
  heat2_k<<<dim3(16, CB), dim3(256), 0, stream>>>(exe, S, img, heat, out_img);
  topk_k<<<dim3(CB), dim3(1024), 0, stream>>>(heat, qids, qbuf, out_crd);
  flash_k<<<dim3(64, CB), dim3(256), 0, stream>>>(
      Xt, St, img, mask, Wv, qids, out_img, qbuf);
  qhead_k<<<dim3(CB*NQP), dim3(256), 0, stream>>>(qbuf, lng, lnb, W1, b1, W2, b2);
}